// Round 11
// baseline (171.881 us; speedup 1.0000x reference)
//
#include <hip/hip_runtime.h>
#include <hip/hip_bf16.h>
#include <cstdint>

// MxDNA deformable conv block, MI355X/gfx950.
// K2: W repack to FRAGMENT-LINEAR bf16 WB2[(kk*256+d)*32 + (kap&31)];
// K3: fused coef + gather-lerp + bf16 MFMA GEMM (M=65536, N=256, Kred=768).
// Round 5: XCD swizzle. Round 6: BM64xBN256 512thr (62.5us gemm).
// Round 7/8: B direct-from-global regressed; B stays in LDS.
// Round 9: coef fusion + coalesced WB2 staging (157us total, gemm 75).
// Round 10/11: spill lessons (reg cap, static indices only).
// Round 12: conflicts 13.4->8.65M, dur unchanged -> off critical path.
// Round 13: ping-pong prefetch regs -- neutral (issue distance not the stall).
// Round 14: lgkm-only barrier -- slight regression; vmcnt drain was never
// the stall. Reverted to __syncthreads. Re-derived: b128 frag reads at
// pitch-40 are at the inherent 8-dword/bank floor (not conflicts); no pipe
// >50% busy; residual idleness = 8-wave barrier convergence jitter with
// only 2 blocks/CU to interleave.
// Round 15: 3 blocks/CU. wlds (6KB) aliased onto Bs[0] (dead until first
// packstore; __syncthreads after coef phase guards the alias -- structure
// R10 ran correctly) -> LDS 57,344 -> 51,200 <= 160K/3. 24 waves/CU
// (6/SIMD), +50% TLP to fill barrier bubbles. launch_bounds (512,6).

#define N_TOK 8192
#define DIM   256
#define KW    768        // reduction length K*D
#define BM    64
#define BN    256
#define BK    32

typedef unsigned short u16;
typedef __attribute__((ext_vector_type(4))) float    floatx4;
typedef __attribute__((ext_vector_type(8))) __bf16   bf16x8;
typedef __attribute__((ext_vector_type(8))) u16      ushortx8;

__device__ __forceinline__ u16 f32_to_bf16_rne(float f) {
    uint32_t u = __float_as_uint(f);
    u += 0x7fffu + ((u >> 16) & 1u);
    return (u16)(u >> 16);
}

// ---------------- Kernel 2: repack weight, fragment-linear ----------------
// kap = k*256+e (reduction index); slice kk = kap>>5 holds a contiguous
// 16 KB block of 256 rows (d) x 32 shorts (kap&31).
__global__ __launch_bounds__(256) void packw_kernel(
    const float* __restrict__ W, u16* __restrict__ WB2)
{
    const int d = blockIdx.x;
    const int e = threadIdx.x;
#pragma unroll
    for (int k = 0; k < 3; ++k) {
        const int kap = k * 256 + e;
        WB2[((size_t)((kap >> 5) * 256 + d)) * 32 + (kap & 31)] =
            f32_to_bf16_rne(W[d * KW + e * 3 + k]);
    }
}

// ---------------- Kernel 3: fused coef + gather/lerp + MFMA GEMM ----------------
// block = 512 thr (8 waves), tile 64(M) x 256(N), BK=32, 24 K-iters.
// Wave tile 32x64: acc 2x4 frags. A+B in LDS dbuf (rows padded to 40
// shorts), single end-of-iter barrier, ping-pong prefetch register sets.
__global__ __launch_bounds__(512, 6) void deform_gemm_kernel(
    const float* __restrict__ x, const float* __restrict__ offw,
    const float* __restrict__ modw, const u16* __restrict__ WB2,
    float* __restrict__ out)
{
    __shared__ __align__(16) u16   As[2][BM * 40];   // 2 x  5120 B
    __shared__ __align__(16) u16   Bs[2][BN * 40];   // 2 x 20480 B
    float* wlds = (float*)&Bs[0][0];                 // 6 KB alias, dead after coef phase

    const int tid  = threadIdx.x;
    const int wave = tid >> 6;
    const int lane = tid & 63;

    // XCD-aware bijective swizzle: 1024 blocks, hw xcd = b % 8.
    const int raw   = blockIdx.x;
    const int xcd   = raw & 7;
    const int lidx  = raw >> 3;              // 0..127 within XCD
    const int mtile = xcd * 128 + lidx;
    const int t0 = mtile * BM;
    const float* xb = x + (size_t)(t0 / N_TOK) * N_TOK * DIM;  // batch base (BM | N_TOK)

    // A staging role: token tl (0..63), 4-float column segment sub (0..7)
    const int tl  = tid >> 3;
    const int sub = tid & 7;

    const int wm = (wave & 1) * 32;   // wave M half
    const int wn = (wave >> 1) * 64;  // wave N quarter
    const int lrow = lane & 15;
    const int lq   = lane >> 4;

    // ---- fused coef computation for token t0+tl (8 threads/token) ----
    if (tid < 192)      ((float4*)wlds)[tid] = ((const float4*)offw)[tid];
    else if (tid < 384) ((float4*)wlds)[tid] = ((const float4*)modw)[tid - 192];
    __syncthreads();

    float s[6];
    {
        const float* xr = x + (size_t)(t0 + tl) * DIM + sub * 32;
        float4 xv[8];
#pragma unroll
        for (int i = 0; i < 8; ++i)
            xv[i] = ((const float4*)xr)[(i + sub) & 7];   // rotated ADDRESS, static reg index
#pragma unroll
        for (int w = 0; w < 6; ++w) {
            const float4* wr = (const float4*)(wlds + w * DIM + sub * 32);
            float a = 0.f;
#pragma unroll
            for (int i = 0; i < 8; ++i) {
                float4 wv = wr[(i + sub) & 7];   // rotated LDS address: conflict-free
                a += xv[i].x * wv.x + xv[i].y * wv.y + xv[i].z * wv.z + xv[i].w * wv.w;
            }
            s[w] = a;
        }
    }
#pragma unroll
    for (int m = 1; m < 8; m <<= 1)
#pragma unroll
        for (int w = 0; w < 6; ++w) s[w] += __shfl_xor(s[w], m, 64);

    int fi0, fi1, fi2, ci0, ci1, ci2;
    float wa0, wa1, wa2, wc0, wc1, wc2;
    {
        const int n = (t0 + tl) & (N_TOK - 1);
#pragma unroll
        for (int k = 0; k < 3; ++k) {
            float pos   = (float)(n + k - 1) + s[k];
            bool  valid = (pos >= 0.0f) && (pos < (float)N_TOK);
            float ff = floorf(pos);
            ff = fminf(fmaxf(ff, 0.0f), (float)(N_TOK - 1));
            int   fi = (int)ff;
            int   ci = min(fi + 1, N_TOK - 1);
            float wc = pos - ff;
            float m  = valid ? (1.0f / (1.0f + expf(-s[3 + k]))) : 0.0f;
            float wa = (1.0f - wc) * m;
            float wcm = wc * m;
            if (k == 0) { fi0 = fi; ci0 = ci; wa0 = wa; wc0 = wcm; }
            if (k == 1) { fi1 = fi; ci1 = ci; wa1 = wa; wc1 = wcm; }
            if (k == 2) { fi2 = fi; ci2 = ci; wa2 = wa; wc2 = wcm; }
        }
    }
    __syncthreads();     // all wlds reads complete before Bs[0] is overwritten

    // ---- ping-pong prefetch register sets (statically named) ----
    float4 pfA, pcA, pfB, pcB;
    uint4  pbA0, pbA1, pbB0, pbB1;

    auto loadgA = [&](int kk) {
        const int tap = kk >> 3;
        const int fi = (tap == 0) ? fi0 : (tap == 1 ? fi1 : fi2);
        const int ci = (tap == 0) ? ci0 : (tap == 1 ? ci1 : ci2);
        const int e0 = (kk & 7) * 32 + sub * 4;
        pfA = *(const float4*)(xb + (size_t)fi * DIM + e0);
        pcA = *(const float4*)(xb + (size_t)ci * DIM + e0);
        const uint4* g = (const uint4*)(WB2 + (size_t)kk * 8192 + (size_t)tid * 16);
        pbA0 = g[0];
        pbA1 = g[1];
    };
    auto loadgB = [&](int kk) {
        const int tap = kk >> 3;
        const int fi = (tap == 0) ? fi0 : (tap == 1 ? fi1 : fi2);
        const int ci = (tap == 0) ? ci0 : (tap == 1 ? ci1 : ci2);
        const int e0 = (kk & 7) * 32 + sub * 4;
        pfB = *(const float4*)(xb + (size_t)fi * DIM + e0);
        pcB = *(const float4*)(xb + (size_t)ci * DIM + e0);
        const uint4* g = (const uint4*)(WB2 + (size_t)kk * 8192 + (size_t)tid * 16);
        pbB0 = g[0];
        pbB1 = g[1];
    };

    auto packstoreA = [&](int buf, int kk) {
        const int tap = kk >> 3;
        const float wA = (tap == 0) ? wa0 : (tap == 1 ? wa1 : wa2);
        const float wC = (tap == 0) ? wc0 : (tap == 1 ? wc1 : wc2);
        float r0 = wA * pfA.x + wC * pcA.x;
        float r1 = wA * pfA.y + wC * pcA.y;
        float r2 = wA * pfA.z + wC * pcA.z;
        float r3 = wA * pfA.w + wC * pcA.w;
        uint32_t p0 = __builtin_amdgcn_perm(__float_as_uint(r1), __float_as_uint(r0), 0x07060302u);
        uint32_t p1 = __builtin_amdgcn_perm(__float_as_uint(r3), __float_as_uint(r2), 0x07060302u);
        *(uint2*)&As[buf][tl * 40 + sub * 4] = make_uint2(p0, p1);
        uint4* bdst = (uint4*)&Bs[buf][(tid >> 1) * 40 + (tid & 1) * 16];
        bdst[0] = pbA0;
        bdst[1] = pbA1;
    };
    auto packstoreB = [&](int buf, int kk) {
        const int tap = kk >> 3;
        const float wA = (tap == 0) ? wa0 : (tap == 1 ? wa1 : wa2);
        const float wC = (tap == 0) ? wc0 : (tap == 1 ? wc1 : wc2);
        float r0 = wA * pfB.x + wC * pcB.x;
        float r1 = wA * pfB.y + wC * pcB.y;
        float r2 = wA * pfB.z + wC * pcB.z;
        float r3 = wA * pfB.w + wC * pcB.w;
        uint32_t p0 = __builtin_amdgcn_perm(__float_as_uint(r1), __float_as_uint(r0), 0x07060302u);
        uint32_t p1 = __builtin_amdgcn_perm(__float_as_uint(r3), __float_as_uint(r2), 0x07060302u);
        *(uint2*)&As[buf][tl * 40 + sub * 4] = make_uint2(p0, p1);
        uint4* bdst = (uint4*)&Bs[buf][(tid >> 1) * 40 + (tid & 1) * 16];
        bdst[0] = pbB0;
        bdst[1] = pbB1;
    };

    floatx4 acc[2][4];
#pragma unroll
    for (int i = 0; i < 2; ++i)
#pragma unroll
        for (int j = 0; j < 4; ++j) acc[i][j] = (floatx4){0.f, 0.f, 0.f, 0.f};

    // prologue: slice 0 -> setA -> buf0; slice 1 -> setB (held in regs)
    loadgA(0);
    loadgB(1);
    packstoreA(0, 0);
    __syncthreads();                 // buf0 visible

    auto mfma_step = [&](int cur) {
        bf16x8 af[2], bfv[4];
#pragma unroll
        for (int i = 0; i < 2; ++i)
            af[i] = __builtin_bit_cast(bf16x8, *(const ushortx8*)&As[cur][(wm + i * 16 + lrow) * 40 + lq * 8]);
#pragma unroll
        for (int j = 0; j < 4; ++j)
            bfv[j] = __builtin_bit_cast(bf16x8, *(const ushortx8*)&Bs[cur][(wn + j * 16 + lrow) * 40 + lq * 8]);
#pragma unroll
        for (int i = 0; i < 2; ++i) {
            acc[i][0] = __builtin_amdgcn_mfma_f32_16x16x32_bf16(af[i], bfv[0], acc[i][0], 0, 0, 0);
            acc[i][1] = __builtin_amdgcn_mfma_f32_16x16x32_bf16(af[i], bfv[1], acc[i][1], 0, 0, 0);
            acc[i][2] = __builtin_amdgcn_mfma_f32_16x16x32_bf16(af[i], bfv[2], acc[i][2], 0, 0, 0);
            acc[i][3] = __builtin_amdgcn_mfma_f32_16x16x32_bf16(af[i], bfv[3], acc[i][3], 0, 0, 0);
        }
    };

    for (int kk = 0; kk < 24; kk += 2) {
        // ---- even sub-iter: consume buf0 (slice kk) ----
        if (kk < 22) loadgA(kk + 2);     // issue slice kk+2 loads
        packstoreB(1, kk + 1);           // stage slice kk+1 -> buf1 (setB, loaded 1 iter ago)
        mfma_step(0);
        __syncthreads();

        // ---- odd sub-iter: consume buf1 (slice kk+1) ----
        if (kk < 22) {
            loadgB(kk + 3);              // issue slice kk+3 loads
            packstoreA(0, kk + 2);       // stage slice kk+2 -> buf0 (setA)
        }
        mfma_step(1);
        __syncthreads();
    }

    // ---- epilogue: C/D layout col = lane&15, row = (lane>>4)*4 + reg
#pragma unroll
    for (int i = 0; i < 2; ++i) {
#pragma unroll
        for (int r = 0; r < 4; ++r) {
            const int token = t0 + wm + i * 16 + lq * 4 + r;
            float* op = out + (size_t)token * DIM + wn + lrow;
#pragma unroll
            for (int j = 0; j < 4; ++j) op[j * 16] = acc[i][j][r];
        }
    }
}

extern "C" void kernel_launch(void* const* d_in, const int* in_sizes, int n_in,
                              void* d_out, int out_size, void* d_ws, size_t ws_size,
                              hipStream_t stream)
{
    const float* x    = (const float*)d_in[0];  // (8, 8192, 256)
    const float* offw = (const float*)d_in[1];  // (3, 256)
    const float* modw = (const float*)d_in[2];  // (3, 256)
    const float* W    = (const float*)d_in[3];  // (256, 256, 3)
    float* out = (float*)d_out;                 // (8, 8192, 256)

    const int tot_tok = 8 * N_TOK;              // 65536
    u16* WB2 = (u16*)d_ws;                      // 393,216 B fragment-linear weight

    packw_kernel<<<DIM, 256, 0, stream>>>(W, WB2);
    deform_gemm_kernel<<<tot_tok / BM, 512, 0, stream>>>(x, offw, modw, WB2, out);
}

// Round 12
// 161.511 us; speedup vs baseline: 1.0642x; 1.0642x over previous
//
#include <hip/hip_runtime.h>
#include <hip/hip_bf16.h>
#include <cstdint>

// MxDNA deformable conv block, MI355X/gfx950.
// K2: W repack to FRAGMENT-LINEAR bf16 WB2[(kk*256+d)*32 + (kap&31)];
// K3: fused coef + gather-lerp + bf16 MFMA GEMM (M=65536, N=256, Kred=768).
// Round 5: XCD swizzle. Round 6: BM64xBN256 512thr (62.5us gemm).
// Round 7/8: B direct-from-global regressed; B stays in LDS.
// Round 9: coef fusion + coalesced WB2 staging (157us total, gemm 75).
// Round 10/11: spill lessons (reg cap, static indices only).
// Round 12: conflicts 13.4->8.65M, dur unchanged -> off critical path.
// Round 13: ping-pong prefetch regs -- neutral. Round 14: lgkm-only
// barrier -- regression; reverted.
// Round 15 (CONTAMINATED): wlds alias + launch_bounds(512,6). The 6 forced
// VGPR 64->40 -> prefetch set rematerialized (FETCH 77->121 MB, ~2x gather
// issue) -> gemm 84. Occupancy did rise 36->43. TLP hypothesis untested.
// Round 16: clean A/B -- wlds alias ONLY (LDS 57,344->51,200 -> 3 blk/CU,
// 24 waves), launch_bounds back to (512,4) so VGPR stays 64 and the
// ping-pong prefetch survives. One-token diff from R15.

#define N_TOK 8192
#define DIM   256
#define KW    768        // reduction length K*D
#define BM    64
#define BN    256
#define BK    32

typedef unsigned short u16;
typedef __attribute__((ext_vector_type(4))) float    floatx4;
typedef __attribute__((ext_vector_type(8))) __bf16   bf16x8;
typedef __attribute__((ext_vector_type(8))) u16      ushortx8;

__device__ __forceinline__ u16 f32_to_bf16_rne(float f) {
    uint32_t u = __float_as_uint(f);
    u += 0x7fffu + ((u >> 16) & 1u);
    return (u16)(u >> 16);
}

// ---------------- Kernel 2: repack weight, fragment-linear ----------------
// kap = k*256+e (reduction index); slice kk = kap>>5 holds a contiguous
// 16 KB block of 256 rows (d) x 32 shorts (kap&31).
__global__ __launch_bounds__(256) void packw_kernel(
    const float* __restrict__ W, u16* __restrict__ WB2)
{
    const int d = blockIdx.x;
    const int e = threadIdx.x;
#pragma unroll
    for (int k = 0; k < 3; ++k) {
        const int kap = k * 256 + e;
        WB2[((size_t)((kap >> 5) * 256 + d)) * 32 + (kap & 31)] =
            f32_to_bf16_rne(W[d * KW + e * 3 + k]);
    }
}

// ---------------- Kernel 3: fused coef + gather/lerp + MFMA GEMM ----------------
// block = 512 thr (8 waves), tile 64(M) x 256(N), BK=32, 24 K-iters.
// Wave tile 32x64: acc 2x4 frags. A+B in LDS dbuf (rows padded to 40
// shorts), single end-of-iter barrier, ping-pong prefetch register sets.
// LDS 51,200 B -> 3 blocks/CU; VGPR 64 -> not register-limited.
__global__ __launch_bounds__(512, 4) void deform_gemm_kernel(
    const float* __restrict__ x, const float* __restrict__ offw,
    const float* __restrict__ modw, const u16* __restrict__ WB2,
    float* __restrict__ out)
{
    __shared__ __align__(16) u16   As[2][BM * 40];   // 2 x  5120 B
    __shared__ __align__(16) u16   Bs[2][BN * 40];   // 2 x 20480 B
    float* wlds = (float*)&Bs[0][0];                 // 6 KB alias, dead after coef phase

    const int tid  = threadIdx.x;
    const int wave = tid >> 6;
    const int lane = tid & 63;

    // XCD-aware bijective swizzle: 1024 blocks, hw xcd = b % 8.
    const int raw   = blockIdx.x;
    const int xcd   = raw & 7;
    const int lidx  = raw >> 3;              // 0..127 within XCD
    const int mtile = xcd * 128 + lidx;
    const int t0 = mtile * BM;
    const float* xb = x + (size_t)(t0 / N_TOK) * N_TOK * DIM;  // batch base (BM | N_TOK)

    // A staging role: token tl (0..63), 4-float column segment sub (0..7)
    const int tl  = tid >> 3;
    const int sub = tid & 7;

    const int wm = (wave & 1) * 32;   // wave M half
    const int wn = (wave >> 1) * 64;  // wave N quarter
    const int lrow = lane & 15;
    const int lq   = lane >> 4;

    // ---- fused coef computation for token t0+tl (8 threads/token) ----
    if (tid < 192)      ((float4*)wlds)[tid] = ((const float4*)offw)[tid];
    else if (tid < 384) ((float4*)wlds)[tid] = ((const float4*)modw)[tid - 192];
    __syncthreads();

    float s[6];
    {
        const float* xr = x + (size_t)(t0 + tl) * DIM + sub * 32;
        float4 xv[8];
#pragma unroll
        for (int i = 0; i < 8; ++i)
            xv[i] = ((const float4*)xr)[(i + sub) & 7];   // rotated ADDRESS, static reg index
#pragma unroll
        for (int w = 0; w < 6; ++w) {
            const float4* wr = (const float4*)(wlds + w * DIM + sub * 32);
            float a = 0.f;
#pragma unroll
            for (int i = 0; i < 8; ++i) {
                float4 wv = wr[(i + sub) & 7];   // rotated LDS address: conflict-free
                a += xv[i].x * wv.x + xv[i].y * wv.y + xv[i].z * wv.z + xv[i].w * wv.w;
            }
            s[w] = a;
        }
    }
#pragma unroll
    for (int m = 1; m < 8; m <<= 1)
#pragma unroll
        for (int w = 0; w < 6; ++w) s[w] += __shfl_xor(s[w], m, 64);

    int fi0, fi1, fi2, ci0, ci1, ci2;
    float wa0, wa1, wa2, wc0, wc1, wc2;
    {
        const int n = (t0 + tl) & (N_TOK - 1);
#pragma unroll
        for (int k = 0; k < 3; ++k) {
            float pos   = (float)(n + k - 1) + s[k];
            bool  valid = (pos >= 0.0f) && (pos < (float)N_TOK);
            float ff = floorf(pos);
            ff = fminf(fmaxf(ff, 0.0f), (float)(N_TOK - 1));
            int   fi = (int)ff;
            int   ci = min(fi + 1, N_TOK - 1);
            float wc = pos - ff;
            float m  = valid ? (1.0f / (1.0f + expf(-s[3 + k]))) : 0.0f;
            float wa = (1.0f - wc) * m;
            float wcm = wc * m;
            if (k == 0) { fi0 = fi; ci0 = ci; wa0 = wa; wc0 = wcm; }
            if (k == 1) { fi1 = fi; ci1 = ci; wa1 = wa; wc1 = wcm; }
            if (k == 2) { fi2 = fi; ci2 = ci; wa2 = wa; wc2 = wcm; }
        }
    }
    __syncthreads();     // all wlds reads complete before Bs[0] is overwritten

    // ---- ping-pong prefetch register sets (statically named) ----
    float4 pfA, pcA, pfB, pcB;
    uint4  pbA0, pbA1, pbB0, pbB1;

    auto loadgA = [&](int kk) {
        const int tap = kk >> 3;
        const int fi = (tap == 0) ? fi0 : (tap == 1 ? fi1 : fi2);
        const int ci = (tap == 0) ? ci0 : (tap == 1 ? ci1 : ci2);
        const int e0 = (kk & 7) * 32 + sub * 4;
        pfA = *(const float4*)(xb + (size_t)fi * DIM + e0);
        pcA = *(const float4*)(xb + (size_t)ci * DIM + e0);
        const uint4* g = (const uint4*)(WB2 + (size_t)kk * 8192 + (size_t)tid * 16);
        pbA0 = g[0];
        pbA1 = g[1];
    };
    auto loadgB = [&](int kk) {
        const int tap = kk >> 3;
        const int fi = (tap == 0) ? fi0 : (tap == 1 ? fi1 : fi2);
        const int ci = (tap == 0) ? ci0 : (tap == 1 ? ci1 : ci2);
        const int e0 = (kk & 7) * 32 + sub * 4;
        pfB = *(const float4*)(xb + (size_t)fi * DIM + e0);
        pcB = *(const float4*)(xb + (size_t)ci * DIM + e0);
        const uint4* g = (const uint4*)(WB2 + (size_t)kk * 8192 + (size_t)tid * 16);
        pbB0 = g[0];
        pbB1 = g[1];
    };

    auto packstoreA = [&](int buf, int kk) {
        const int tap = kk >> 3;
        const float wA = (tap == 0) ? wa0 : (tap == 1 ? wa1 : wa2);
        const float wC = (tap == 0) ? wc0 : (tap == 1 ? wc1 : wc2);
        float r0 = wA * pfA.x + wC * pcA.x;
        float r1 = wA * pfA.y + wC * pcA.y;
        float r2 = wA * pfA.z + wC * pcA.z;
        float r3 = wA * pfA.w + wC * pcA.w;
        uint32_t p0 = __builtin_amdgcn_perm(__float_as_uint(r1), __float_as_uint(r0), 0x07060302u);
        uint32_t p1 = __builtin_amdgcn_perm(__float_as_uint(r3), __float_as_uint(r2), 0x07060302u);
        *(uint2*)&As[buf][tl * 40 + sub * 4] = make_uint2(p0, p1);
        uint4* bdst = (uint4*)&Bs[buf][(tid >> 1) * 40 + (tid & 1) * 16];
        bdst[0] = pbA0;
        bdst[1] = pbA1;
    };
    auto packstoreB = [&](int buf, int kk) {
        const int tap = kk >> 3;
        const float wA = (tap == 0) ? wa0 : (tap == 1 ? wa1 : wa2);
        const float wC = (tap == 0) ? wc0 : (tap == 1 ? wc1 : wc2);
        float r0 = wA * pfB.x + wC * pcB.x;
        float r1 = wA * pfB.y + wC * pcB.y;
        float r2 = wA * pfB.z + wC * pcB.z;
        float r3 = wA * pfB.w + wC * pcB.w;
        uint32_t p0 = __builtin_amdgcn_perm(__float_as_uint(r1), __float_as_uint(r0), 0x07060302u);
        uint32_t p1 = __builtin_amdgcn_perm(__float_as_uint(r3), __float_as_uint(r2), 0x07060302u);
        *(uint2*)&As[buf][tl * 40 + sub * 4] = make_uint2(p0, p1);
        uint4* bdst = (uint4*)&Bs[buf][(tid >> 1) * 40 + (tid & 1) * 16];
        bdst[0] = pbB0;
        bdst[1] = pbB1;
    };

    floatx4 acc[2][4];
#pragma unroll
    for (int i = 0; i < 2; ++i)
#pragma unroll
        for (int j = 0; j < 4; ++j) acc[i][j] = (floatx4){0.f, 0.f, 0.f, 0.f};

    // prologue: slice 0 -> setA -> buf0; slice 1 -> setB (held in regs)
    loadgA(0);
    loadgB(1);
    packstoreA(0, 0);
    __syncthreads();                 // buf0 visible

    auto mfma_step = [&](int cur) {
        bf16x8 af[2], bfv[4];
#pragma unroll
        for (int i = 0; i < 2; ++i)
            af[i] = __builtin_bit_cast(bf16x8, *(const ushortx8*)&As[cur][(wm + i * 16 + lrow) * 40 + lq * 8]);
#pragma unroll
        for (int j = 0; j < 4; ++j)
            bfv[j] = __builtin_bit_cast(bf16x8, *(const ushortx8*)&Bs[cur][(wn + j * 16 + lrow) * 40 + lq * 8]);
#pragma unroll
        for (int i = 0; i < 2; ++i) {
            acc[i][0] = __builtin_amdgcn_mfma_f32_16x16x32_bf16(af[i], bfv[0], acc[i][0], 0, 0, 0);
            acc[i][1] = __builtin_amdgcn_mfma_f32_16x16x32_bf16(af[i], bfv[1], acc[i][1], 0, 0, 0);
            acc[i][2] = __builtin_amdgcn_mfma_f32_16x16x32_bf16(af[i], bfv[2], acc[i][2], 0, 0, 0);
            acc[i][3] = __builtin_amdgcn_mfma_f32_16x16x32_bf16(af[i], bfv[3], acc[i][3], 0, 0, 0);
        }
    };

    for (int kk = 0; kk < 24; kk += 2) {
        // ---- even sub-iter: consume buf0 (slice kk) ----
        if (kk < 22) loadgA(kk + 2);     // issue slice kk+2 loads
        packstoreB(1, kk + 1);           // stage slice kk+1 -> buf1 (setB, loaded 1 iter ago)
        mfma_step(0);
        __syncthreads();

        // ---- odd sub-iter: consume buf1 (slice kk+1) ----
        if (kk < 22) {
            loadgB(kk + 3);              // issue slice kk+3 loads
            packstoreA(0, kk + 2);       // stage slice kk+2 -> buf0 (setA)
        }
        mfma_step(1);
        __syncthreads();
    }

    // ---- epilogue: C/D layout col = lane&15, row = (lane>>4)*4 + reg
#pragma unroll
    for (int i = 0; i < 2; ++i) {
#pragma unroll
        for (int r = 0; r < 4; ++r) {
            const int token = t0 + wm + i * 16 + lq * 4 + r;
            float* op = out + (size_t)token * DIM + wn + lrow;
#pragma unroll
            for (int j = 0; j < 4; ++j) op[j * 16] = acc[i][j][r];
        }
    }
}

extern "C" void kernel_launch(void* const* d_in, const int* in_sizes, int n_in,
                              void* d_out, int out_size, void* d_ws, size_t ws_size,
                              hipStream_t stream)
{
    const float* x    = (const float*)d_in[0];  // (8, 8192, 256)
    const float* offw = (const float*)d_in[1];  // (3, 256)
    const float* modw = (const float*)d_in[2];  // (3, 256)
    const float* W    = (const float*)d_in[3];  // (256, 256, 3)
    float* out = (float*)d_out;                 // (8, 8192, 256)

    const int tot_tok = 8 * N_TOK;              // 65536
    u16* WB2 = (u16*)d_ws;                      // 393,216 B fragment-linear weight

    packw_kernel<<<DIM, 256, 0, stream>>>(W, WB2);
    deform_gemm_kernel<<<tot_tok / BM, 512, 0, stream>>>(x, offw, modw, WB2, out);
}